// Round 1
// baseline (659.585 us; speedup 1.0000x reference)
//
#include <hip/hip_runtime.h>
#include <math.h>

#define B_ 8
#define N_ 32
#define M_ 32
#define HW 192

typedef __attribute__((ext_vector_type(8))) short short8;
typedef __attribute__((ext_vector_type(4))) float float4_;

__device__ inline unsigned short f2bf(float f) {
    unsigned int b = __float_as_uint(f);
    b += 0x7FFF + ((b >> 16) & 1);   // RNE
    return (unsigned short)(b >> 16);
}
__device__ inline float bf2f(unsigned short u) {
    return __uint_as_float((unsigned int)u << 16);
}

union U8 { short8 s; unsigned int u[4]; };

// ---- prep kernel: zero counters/pooled + build bf16 MFMA A-fragments ----
// a1A[c][lane][j] : o=lane&15 (o<9 real, else 0), n=(lane>>4)*8+j, p=c
// wA [c][mt][lane][j] : m=mt*16+(lane&15), n=(lane>>4)*8+j, p=c
__global__ __launch_bounds__(256) void prep_kernel(
    const float* __restrict__ a1w, const float* __restrict__ weight,
    int* __restrict__ wsz, unsigned short* __restrict__ a1A,
    unsigned short* __restrict__ wA) {
    const int c = blockIdx.x, tid = threadIdx.x;
    if (c == 0) {            // zero cnt[8] + pooled[256] region ([0,2048) bytes)
        wsz[tid] = 0;
        wsz[tid + 256] = 0;
    }
    for (int idx = tid; idx < 512; idx += 256) {
        int j = idx & 7, l = idx >> 3;
        int o = l & 15, n = (l >> 4) * 8 + j;
        float v = (o < 9) ? a1w[(o * N_ + n) * 9 + c] : 0.f;
        a1A[c * 512 + idx] = f2bf(v);
    }
    for (int idx = tid; idx < 1024; idx += 256) {
        int j = idx & 7, l = (idx >> 3) & 63, mt = idx >> 9;
        int m = mt * 16 + (l & 15), n = (l >> 4) * 8 + j;
        wA[c * 1024 + idx] = f2bf(weight[(m * N_ + n) * 9 + c]);
    }
}

// ---------- fused kernel: attention1 + attended conv + pooling + bias ----------
// grid = 1024 = 4 blocks/CU * 256 CUs (co-resident by __launch_bounds__(256,4):
// VGPR<=128 and LDS 31.9KB<=40KB). Blocks 0..127 run a second pass for the
// remaining 128 tiles; their pool contribution for that tile is made FIRST
// (before any spin anywhere) so all contributions precede all spins -> no
// deadlock. Spins are bounded so a failure is a wrong answer, not a hang.
__global__ __launch_bounds__(256, 4) void laconv_fused(
    const float* __restrict__ x, const float* __restrict__ a1b,
    const float* __restrict__ a2w, const float* __restrict__ a2b,
    const float* __restrict__ a3w, const float* __restrict__ a3b,
    const unsigned short* __restrict__ a1A, const unsigned short* __restrict__ wA,
    float* __restrict__ pooled, int* __restrict__ cnt,
    const float* __restrict__ b1w, const float* __restrict__ b1b,
    const float* __restrict__ b2w, const float* __restrict__ b2b,
    float* __restrict__ out) {
    // xs[pos][n] bf16, pos = r*18+c (18x18 tile+halo), n-stride padded to 40
    __shared__ __align__(16) unsigned short xs[324 * 40];   // 25920 B
    __shared__ unsigned short att_s[9 * 264];               //  4752 B (bf16)
    __shared__ float hsh[M_];
    __shared__ __align__(16) float bias_lds[M_];
    __shared__ float ps[8][32];                             //  1024 B -> 31.9 KB total

    // XCD-affinity: batch = id&7 (round-robin -> one image per XCD),
    // consecutive tiles of an image stay on the same XCD for halo L2 sharing.
    const int id = blockIdx.x;
    const int b = id & 7;
    const int tid = threadIdx.x;
    const int wv = tid >> 6, lane = tid & 63;
    const int tx = lane & 15, ks = lane >> 4;
    const float* xb = x + (size_t)b * N_ * HW * HW;
    const float inv_px = 1.f / (float)(HW * HW);

    // ---- early pool contribution for the second-pass tile (blocks 0..127) ----
    if (id < 128) {
        const int t2 = 128 + (id >> 3);
        const int bx2 = t2 % 12, by2 = t2 / 12;
        const int n = tid >> 3, sub = tid & 7;   // 32 channels x 8 row-pairs
        const float* src = xb + (size_t)n * (HW * HW) + (by2 * 16 + sub * 2) * HW + bx2 * 16;
        float s = 0.f;
#pragma unroll
        for (int rr = 0; rr < 2; ++rr)
#pragma unroll
            for (int q = 0; q < 4; ++q) {
                float4_ v = *(const float4_*)(src + rr * HW + q * 4);
                s += (v[0] + v[1]) + (v[2] + v[3]);
            }
        s += __shfl_down(s, 4, 8);
        s += __shfl_down(s, 2, 8);
        s += __shfl_down(s, 1, 8);
        if (sub == 0) atomicAdd(&pooled[b * 32 + n], s * inv_px);
        __syncthreads();   // drain the atomics (vmcnt) before publishing
        if (tid == 0)
            __hip_atomic_fetch_add(&cnt[b], 1, __ATOMIC_RELEASE, __HIP_MEMORY_SCOPE_AGENT);
    }

    // per-lane base into xs: pixel (ty = wv*4+g, tx), k-slot ks
    const int pb = (wv * 4) * 720 + tx * 40 + ks * 8;
    const float4_ zero4 = {0.f, 0.f, 0.f, 0.f};
    const int npass = (id < 128) ? 2 : 1;

    for (int pass = 0; pass < npass; ++pass) {
        const int t = pass ? (128 + (id >> 3)) : (id >> 3);   // tile 0..143
        const int bx = t % 12, by = t / 12;
        const int th0 = by * 16, tw0 = bx * 16;

        // ---- stage x tile -> LDS transposed [pos][n] bf16; loads-first ----
        float fv[5][8];
        int posv[5], grpv[5];
#pragma unroll
        for (int it0 = 0; it0 < 5; ++it0) {
            int it = tid + it0 * 256;          // < 1280
            int grp = it / 324;                // n-group: n = grp*8 + i
            int pos = it - grp * 324;
            posv[it0] = pos; grpv[it0] = grp;
            int r = pos / 18, cc = pos - r * 18;
            int h = th0 + r - 1, wc = tw0 + cc - 1;
            const float* src = xb + (size_t)(grp * 8) * (HW * HW) + h * HW + wc;
            if (((unsigned)h < HW) && ((unsigned)wc < HW)) {
#pragma unroll
                for (int i = 0; i < 8; ++i) fv[it0][i] = src[i * (HW * HW)];
            } else {
#pragma unroll
                for (int i = 0; i < 8; ++i) fv[it0][i] = 0.f;
            }
        }
        // remainder: it = 1280 + tid, tid < 16  (pos 956.. -> grp 3)
        float fr[8];
        int posr = 0;
        if (tid < 16) {
            int it = 1280 + tid;
            int pos = it - 3 * 324;
            posr = pos;
            int r = pos / 18, cc = pos - r * 18;
            int h = th0 + r - 1, wc = tw0 + cc - 1;
            const float* src = xb + (size_t)24 * (HW * HW) + h * HW + wc;
            if (((unsigned)h < HW) && ((unsigned)wc < HW)) {
#pragma unroll
                for (int i = 0; i < 8; ++i) fr[i] = src[i * (HW * HW)];
            } else {
#pragma unroll
                for (int i = 0; i < 8; ++i) fr[i] = 0.f;
            }
        }
        // pack + LDS write after all loads are in flight
#pragma unroll
        for (int it0 = 0; it0 < 5; ++it0) {
            U8 tt;
#pragma unroll
            for (int i = 0; i < 4; ++i)
                tt.u[i] = (unsigned)f2bf(fv[it0][2 * i]) |
                          ((unsigned)f2bf(fv[it0][2 * i + 1]) << 16);
            *(short8*)&xs[posv[it0] * 40 + grpv[it0] * 8] = tt.s;
        }
        if (tid < 16) {
            U8 tt;
#pragma unroll
            for (int i = 0; i < 4; ++i)
                tt.u[i] = (unsigned)f2bf(fr[2 * i]) | ((unsigned)f2bf(fr[2 * i + 1]) << 16);
            *(short8*)&xs[posr * 40 + 24] = tt.s;
        }
        __syncthreads();   // A: tile staged

        // ---- attention1 conv via MFMA: aacc[o=ks*4+reg][pix=tx] per group ----
        float4_ aacc[4];
#pragma unroll
        for (int g = 0; g < 4; ++g) aacc[g] = zero4;
#pragma unroll
        for (int c = 0; c < 9; ++c) {
            short8 aA = ((const short8*)a1A)[c * 64 + lane];
            const int coff = (c / 3) * 720 + (c % 3) * 40;
#pragma unroll
            for (int g = 0; g < 4; ++g) {
                short8 bP = *(const short8*)&xs[pb + g * 720 + coff];
                aacc[g] = __builtin_amdgcn_mfma_f32_16x16x32_bf16(aA, bP, aacc[g], 0, 0, 0);
            }
        }
        // ---- pool partial from the staged interior (pass 0 tiles only) ----
        if (pass == 0) {
            const int n = tid & 31, part = tid >> 5;
            float s = 0.f;
#pragma unroll
            for (int rr = 0; rr < 2; ++rr) {
                const int base = ((part * 2 + rr + 1) * 18 + 1) * 40 + n;
#pragma unroll
                for (int c2 = 0; c2 < 16; ++c2) s += bf2f(xs[base + c2 * 40]);
            }
            ps[part][n] = s;
        }
        // write raw conv results (bf16) to att_s[o][pix]
#pragma unroll
        for (int g = 0; g < 4; ++g) {
#pragma unroll
            for (int reg = 0; reg < 4; ++reg) {
                int o = ks * 4 + reg;
                if (o < 9) att_s[o * 264 + (wv * 4 + g) * 16 + tx] = f2bf(aacc[g][reg]);
            }
        }
        __syncthreads();   // B: att_s + ps complete

        // reduce pool partials; atomics fly during the MLP + main loop
        if (pass == 0 && tid < 32) {
            float pc = 0.f;
#pragma unroll
            for (int k2 = 0; k2 < 8; ++k2) pc += ps[k2][tid];
            atomicAdd(&pooled[b * 32 + tid], pc * inv_px);
        }

        // ---- per-pixel MLP 9->9->9 + sigmoid (thread tid = pixel tid) ----
        float t1[9], t2[9], attv[9];
#pragma unroll
        for (int o = 0; o < 9; ++o)
            t1[o] = fmaxf(bf2f(att_s[o * 264 + tid]) + a1b[o], 0.f);
#pragma unroll
        for (int o2 = 0; o2 < 9; ++o2) {
            float s = a2b[o2];
#pragma unroll
            for (int o = 0; o < 9; ++o) s += a2w[o2 * 9 + o] * t1[o];
            t2[o2] = fmaxf(s, 0.f);
        }
#pragma unroll
        for (int o3 = 0; o3 < 9; ++o3) {
            float s = a3b[o3];
#pragma unroll
            for (int o2 = 0; o2 < 9; ++o2) s += a3w[o3 * 9 + o2] * t2[o2];
            attv[o3] = 1.f / (1.f + __expf(-s));
        }
#pragma unroll
        for (int p = 0; p < 9; ++p) att_s[p * 264 + tid] = f2bf(attv[p]);
        __syncthreads();   // C

        // ---- main einsum: per chunk c, z = W_c · pat_c (zero-C MFMA), then
        //      acc += att * z as float4 vector math (-> v_pk_fma_f32)
        float4_ acc0[4], acc1[4];
#pragma unroll
        for (int g = 0; g < 4; ++g) { acc0[g] = zero4; acc1[g] = zero4; }
#pragma unroll
        for (int c = 0; c < 9; ++c) {
            short8 w0 = ((const short8*)wA)[c * 128 + lane];
            short8 w1 = ((const short8*)wA)[c * 128 + 64 + lane];
            const int coff = (c / 3) * 720 + (c % 3) * 40;
#pragma unroll
            for (int g = 0; g < 4; ++g) {
                short8 bP = *(const short8*)&xs[pb + g * 720 + coff];
                float av = bf2f(att_s[c * 264 + (wv * 4 + g) * 16 + tx]);
                float4_ av4 = {av, av, av, av};
                float4_ z0 = __builtin_amdgcn_mfma_f32_16x16x32_bf16(w0, bP, zero4, 0, 0, 0);
                float4_ z1 = __builtin_amdgcn_mfma_f32_16x16x32_bf16(w1, bP, zero4, 0, 0, 0);
                acc0[g] = acc0[g] + av4 * z0;
                acc1[g] = acc1[g] + av4 * z1;
            }
        }

        // ---- pass-0 tail: publish count, wait for the batch, bias MLP ----
        if (pass == 0) {
            __syncthreads();   // D: drains this block's pooled atomics (vmcnt)
            if (tid == 0) {
                __hip_atomic_fetch_add(&cnt[b], 1, __ATOMIC_RELEASE,
                                       __HIP_MEMORY_SCOPE_AGENT);
                int guard = 0;
                while (__hip_atomic_load(&cnt[b], __ATOMIC_ACQUIRE,
                                         __HIP_MEMORY_SCOPE_AGENT) < 144) {
                    if (++guard > (1 << 17)) break;   // bounded: fail, don't hang
                    __builtin_amdgcn_s_sleep(8);
                }
            }
            __syncthreads();   // E
            if (tid < 32)
                ps[0][tid] = __hip_atomic_load(&pooled[b * 32 + tid], __ATOMIC_RELAXED,
                                               __HIP_MEMORY_SCOPE_AGENT);
            if (tid < M_) {    // wave-0-local: ps[0]/hsh RAW stays in-wave
                float s = b1b[tid];
#pragma unroll
                for (int n = 0; n < N_; n++) s += ps[0][n] * b1w[tid * N_ + n];
                hsh[tid] = fmaxf(s, 0.f);
            }
            if (tid < M_) {
                float s2 = b2b[tid];
#pragma unroll
                for (int q = 0; q < M_; q++) s2 += hsh[q] * b2w[tid * M_ + q];
                bias_lds[tid] = s2;
            }
            __syncthreads();   // F: bias_lds visible to all waves (and pass 1)
        }

        // ---- epilogue: D row = m = mt*16 + ks*4 + reg, col = tx ----
        const int wc = tw0 + tx;
        float4_ bv0 = *(const float4_*)&bias_lds[ks * 4];
        float4_ bv1 = *(const float4_*)&bias_lds[16 + ks * 4];
#pragma unroll
        for (int g = 0; g < 4; ++g) {
            int h = th0 + wv * 4 + g;
#pragma unroll
            for (int reg = 0; reg < 4; ++reg) {
                int m0 = ks * 4 + reg;
                out[((b * M_ + m0) * HW + h) * HW + wc] = acc0[g][reg] + bv0[reg];
                out[((b * M_ + m0 + 16) * HW + h) * HW + wc] = acc1[g][reg] + bv1[reg];
            }
        }
    }
}

extern "C" void kernel_launch(void* const* d_in, const int* in_sizes, int n_in,
                              void* d_out, int out_size, void* d_ws,
                              size_t ws_size, hipStream_t stream) {
    const float* x   = (const float*)d_in[0];
    const float* a1w = (const float*)d_in[1];
    const float* a1b = (const float*)d_in[2];
    const float* a2w = (const float*)d_in[3];
    const float* a2b = (const float*)d_in[4];
    const float* a3w = (const float*)d_in[5];
    const float* a3b = (const float*)d_in[6];
    const float* b1w = (const float*)d_in[7];
    const float* b1b = (const float*)d_in[8];
    const float* b2w = (const float*)d_in[9];
    const float* b2b = (const float*)d_in[10];
    const float* wgt = (const float*)d_in[11];
    float* out = (float*)d_out;

    char* ws = (char*)d_ws;
    int* cnt             = (int*)(ws);                   //   32 B
    float* pooled        = (float*)(ws + 1024);          // 1024 B
    unsigned short* a1A  = (unsigned short*)(ws + 2048); // 9216 B
    unsigned short* wAf  = (unsigned short*)(ws + 11264);// 18432 B

    prep_kernel<<<dim3(9), dim3(256), 0, stream>>>(a1w, wgt, (int*)ws, a1A, wAf);
    laconv_fused<<<dim3(1024), dim3(256), 0, stream>>>(
        x, a1b, a2w, a2b, a3w, a3b, a1A, wAf, pooled, cnt,
        b1w, b1b, b2w, b2b, out);
    (void)in_sizes; (void)n_in; (void)out_size; (void)ws_size;
}

// Round 2
// 145.023 us; speedup vs baseline: 4.5481x; 4.5481x over previous
//
#include <hip/hip_runtime.h>
#include <math.h>

#define B_ 8
#define N_ 32
#define M_ 32
#define HW 192
#define NPIX (HW * HW)          // 36864 pixels per image
#define CONV_BLKS (B_ * 144)    // 1152: convert blocks (256 pixels each)
#define POOL_BLKS (B_ * N_)     // 256: pool blocks (one (b,n) plane each)

typedef __attribute__((ext_vector_type(8))) short short8;
typedef __attribute__((ext_vector_type(4))) float float4_;

__device__ inline unsigned short f2bf(float f) {
    unsigned int b = __float_as_uint(f);
    b += 0x7FFF + ((b >> 16) & 1);   // RNE
    return (unsigned short)(b >> 16);
}
__device__ inline float bf2f(unsigned short u) {
    return __uint_as_float((unsigned int)u << 16);
}

union U8 { short8 s; unsigned int u[4]; };

// ---- kernel 1: convert x -> pixel-major bf16 (xbf[b][pix][n]), pool, prep ----
// blocks [0, 1152): convert one 256-pixel chunk (all 32 channels)
// blocks [1152, 1408): pool one (b,n) plane (f32, exact) -> pooled[bn]
// blocks [1408, 1417): build bf16 MFMA A-fragments for chunk c
__global__ __launch_bounds__(256) void convert_pool_prep(
    const float* __restrict__ x, const float* __restrict__ a1w,
    const float* __restrict__ weight, float* __restrict__ pooled,
    unsigned short* __restrict__ a1A, unsigned short* __restrict__ wA,
    unsigned short* __restrict__ xbf) {
    const int id = blockIdx.x, tid = threadIdx.x;
    if (id < CONV_BLKS) {
        const int b = id / 144, chunk = id - b * 144;
        const int pix = chunk * 256 + tid;           // < 36864 always
        const float* src = x + (size_t)b * N_ * NPIX + pix;
        float v[32];
#pragma unroll
        for (int n = 0; n < N_; ++n) v[n] = src[(size_t)n * NPIX];  // coalesced
        U8 tt;
        unsigned short* dst = xbf + ((size_t)b * NPIX + pix) * 32;
#pragma unroll
        for (int q = 0; q < 4; ++q) {
#pragma unroll
            for (int i = 0; i < 4; ++i)
                tt.u[i] = (unsigned)f2bf(v[q * 8 + 2 * i]) |
                          ((unsigned)f2bf(v[q * 8 + 2 * i + 1]) << 16);
            *(short8*)(dst + q * 8) = tt.s;
        }
        return;
    }
    if (id < CONV_BLKS + POOL_BLKS) {
        const int bn = id - CONV_BLKS;
        const float4_* p = (const float4_*)(x + (size_t)bn * NPIX);
        float s = 0.f;
        for (int i = tid; i < NPIX / 4; i += 256) {
            float4_ v = p[i];
            s += (v[0] + v[1]) + (v[2] + v[3]);
        }
#pragma unroll
        for (int off = 32; off > 0; off >>= 1) s += __shfl_down(s, off, 64);
        __shared__ float red[4];
        if ((tid & 63) == 0) red[tid >> 6] = s;
        __syncthreads();
        if (tid == 0)
            pooled[bn] = (red[0] + red[1] + red[2] + red[3]) * (1.f / NPIX);
        return;
    }
    // prep: a1A[c][lane][j]: o=lane&15 (o<9 real), n=(lane>>4)*8+j, p=c
    //       wA [c][mt][lane][j]: m=mt*16+(lane&15), n=(lane>>4)*8+j, p=c
    const int c = id - (CONV_BLKS + POOL_BLKS);
    for (int idx = tid; idx < 512; idx += 256) {
        int j = idx & 7, l = idx >> 3;
        int o = l & 15, n = (l >> 4) * 8 + j;
        float v = (o < 9) ? a1w[(o * N_ + n) * 9 + c] : 0.f;
        a1A[c * 512 + idx] = f2bf(v);
    }
    for (int idx = tid; idx < 1024; idx += 256) {
        int j = idx & 7, l = (idx >> 3) & 63, mt = idx >> 9;
        int m = mt * 16 + (l & 15), n = (l >> 4) * 8 + j;
        wA[c * 1024 + idx] = f2bf(weight[(m * N_ + n) * 9 + c]);
    }
}

// ---------- fused MFMA kernel: attention1 + attended conv + bias ----------
__global__ __launch_bounds__(256) void laconv_kernel(
    const unsigned short* __restrict__ xbf, const float* __restrict__ a1b,
    const float* __restrict__ a2w, const float* __restrict__ a2b,
    const float* __restrict__ a3w, const float* __restrict__ a3b,
    const unsigned short* __restrict__ a1A, const unsigned short* __restrict__ wA,
    const float* __restrict__ pooled, const float* __restrict__ b1w,
    const float* __restrict__ b1b, const float* __restrict__ b2w,
    const float* __restrict__ b2b, float* __restrict__ out) {
    // xs[pos][n] bf16, pos = r*18+c (18x18 tile+halo), n-stride padded to 40
    __shared__ __align__(16) unsigned short xs[324 * 40];   // 25920 B
    __shared__ unsigned short att_s[9 * 264];               //  4752 B (bf16)
    __shared__ float hsh[M_];
    __shared__ __align__(16) float bias_lds[M_];            // ~30.9 KB -> 5 blk/CU

    // XCD-affinity swizzle: batch = id&7 (round-robin -> one image per XCD),
    // consecutive tiles of an image stay on the same XCD for halo L2 sharing.
    const int id = blockIdx.x;
    const int b = id & 7;
    const int t = id >> 3;           // 0..143
    const int bx = t % 12, by = t / 12;
    const int th0 = by * 16, tw0 = bx * 16;
    const int tid = threadIdx.x;
    const int wv = tid >> 6, lane = tid & 63;
    const int tx = lane & 15, ks = lane >> 4;
    const unsigned short* xb = xbf + (size_t)b * NPIX * 32;

    // ---- stage x tile -> LDS [pos][n] bf16, items = (pos, grp) grp-inner ----
    // item it: pos = it>>2 (18x18), grp = it&3 (channels grp*8..grp*8+7)
    // one ushort8 (16B) load per item from pixel-major xbf; loads-first.
    short8 sv[5];
    int pv[5];
#pragma unroll
    for (int it0 = 0; it0 < 5; ++it0) {
        int it = tid + it0 * 256;          // < 1280
        int pos = it >> 2, grp = it & 3;
        pv[it0] = pos * 40 + grp * 8;
        int r = pos / 18, cc = pos - r * 18;
        int h = th0 + r - 1, wc = tw0 + cc - 1;
        if (((unsigned)h < HW) && ((unsigned)wc < HW)) {
            sv[it0] = *(const short8*)(xb + ((size_t)(h * HW + wc)) * 32 + grp * 8);
        } else {
            sv[it0] = (short8)0;
        }
    }
    short8 svr = (short8)0;
    int pvr = 0;
    if (tid < 16) {
        int it = 1280 + tid;               // 1296 items total
        int pos = it >> 2, grp = it & 3;
        pvr = pos * 40 + grp * 8;
        int r = pos / 18, cc = pos - r * 18;
        int h = th0 + r - 1, wc = tw0 + cc - 1;
        if (((unsigned)h < HW) && ((unsigned)wc < HW))
            svr = *(const short8*)(xb + ((size_t)(h * HW + wc)) * 32 + grp * 8);
    }
#pragma unroll
    for (int it0 = 0; it0 < 5; ++it0) *(short8*)&xs[pv[it0]] = sv[it0];
    if (tid < 16) *(short8*)&xs[pvr] = svr;

    // bias MLP stage 1 (covered by the sync below)
    if (tid < M_) {
        float s = b1b[tid];
#pragma unroll
        for (int n = 0; n < N_; n++) s += pooled[b * N_ + n] * b1w[tid * N_ + n];
        hsh[tid] = fmaxf(s, 0.f);
    }
    __syncthreads();
    // bias MLP stage 2 (bias_lds read only after the att sync below)
    if (tid < M_) {
        float s2 = b2b[tid];
#pragma unroll
        for (int q = 0; q < M_; q++) s2 += hsh[q] * b2w[tid * M_ + q];
        bias_lds[tid] = s2;
    }

    // per-lane base into xs: pixel (ty = wv*4+g, tx), k-slot ks
    const int pb = (wv * 4) * 720 + tx * 40 + ks * 8;
    const float4_ zero4 = {0.f, 0.f, 0.f, 0.f};

    // ---- attention1 conv via MFMA: aacc[o=ks*4+reg][pix=tx] per group ----
    float4_ aacc[4];
#pragma unroll
    for (int g = 0; g < 4; ++g) aacc[g] = zero4;
#pragma unroll
    for (int c = 0; c < 9; ++c) {
        short8 aA = ((const short8*)a1A)[c * 64 + lane];
        const int coff = (c / 3) * 720 + (c % 3) * 40;
#pragma unroll
        for (int g = 0; g < 4; ++g) {
            short8 bP = *(const short8*)&xs[pb + g * 720 + coff];
            aacc[g] = __builtin_amdgcn_mfma_f32_16x16x32_bf16(aA, bP, aacc[g], 0, 0, 0);
        }
    }
    // write raw conv results (bf16) to att_s[o][pix]
#pragma unroll
    for (int g = 0; g < 4; ++g) {
#pragma unroll
        for (int reg = 0; reg < 4; ++reg) {
            int o = ks * 4 + reg;
            if (o < 9) att_s[o * 264 + (wv * 4 + g) * 16 + tx] = f2bf(aacc[g][reg]);
        }
    }
    __syncthreads();

    // ---- per-pixel MLP 9->9->9 + sigmoid (thread tid = pixel tid) ----
    // reads & writes touch only column `tid` of att_s -> no barrier needed
    // between the read phase and the attv write-back.
    float t1[9], t2[9], attv[9];
#pragma unroll
    for (int o = 0; o < 9; ++o)
        t1[o] = fmaxf(bf2f(att_s[o * 264 + tid]) + a1b[o], 0.f);
#pragma unroll
    for (int o2 = 0; o2 < 9; ++o2) {
        float s = a2b[o2];
#pragma unroll
        for (int o = 0; o < 9; ++o) s += a2w[o2 * 9 + o] * t1[o];
        t2[o2] = fmaxf(s, 0.f);
    }
#pragma unroll
    for (int o3 = 0; o3 < 9; ++o3) {
        float s = a3b[o3];
#pragma unroll
        for (int o2 = 0; o2 < 9; ++o2) s += a3w[o3 * 9 + o2] * t2[o2];
        attv[o3] = 1.f / (1.f + __expf(-s));
    }
#pragma unroll
    for (int p = 0; p < 9; ++p) att_s[p * 264 + tid] = f2bf(attv[p]);
    __syncthreads();

    // ---- main einsum: per chunk c, z = W_c · pat_c (zero-C MFMA), then
    //      acc += att * z as float4 vector math (-> v_pk_fma_f32)
    float4_ acc0[4], acc1[4];
#pragma unroll
    for (int g = 0; g < 4; ++g) { acc0[g] = zero4; acc1[g] = zero4; }
#pragma unroll
    for (int c = 0; c < 9; ++c) {
        short8 w0 = ((const short8*)wA)[c * 128 + lane];
        short8 w1 = ((const short8*)wA)[c * 128 + 64 + lane];
        const int coff = (c / 3) * 720 + (c % 3) * 40;
#pragma unroll
        for (int g = 0; g < 4; ++g) {
            short8 bP = *(const short8*)&xs[pb + g * 720 + coff];
            float av = bf2f(att_s[c * 264 + (wv * 4 + g) * 16 + tx]);
            float4_ av4 = {av, av, av, av};
            float4_ z0 = __builtin_amdgcn_mfma_f32_16x16x32_bf16(w0, bP, zero4, 0, 0, 0);
            float4_ z1 = __builtin_amdgcn_mfma_f32_16x16x32_bf16(w1, bP, zero4, 0, 0, 0);
            acc0[g] = acc0[g] + av4 * z0;
            acc1[g] = acc1[g] + av4 * z1;
        }
    }

    // ---- epilogue: D row = m = mt*16 + ks*4 + reg, col = tx ----
    const int wc = tw0 + tx;
    float4_ bv0 = *(const float4_*)&bias_lds[ks * 4];
    float4_ bv1 = *(const float4_*)&bias_lds[16 + ks * 4];
#pragma unroll
    for (int g = 0; g < 4; ++g) {
        int h = th0 + wv * 4 + g;
#pragma unroll
        for (int reg = 0; reg < 4; ++reg) {
            int m0 = ks * 4 + reg;
            out[((b * M_ + m0) * HW + h) * HW + wc] = acc0[g][reg] + bv0[reg];
            out[((b * M_ + m0 + 16) * HW + h) * HW + wc] = acc1[g][reg] + bv1[reg];
        }
    }
}

extern "C" void kernel_launch(void* const* d_in, const int* in_sizes, int n_in,
                              void* d_out, int out_size, void* d_ws,
                              size_t ws_size, hipStream_t stream) {
    const float* x   = (const float*)d_in[0];
    const float* a1w = (const float*)d_in[1];
    const float* a1b = (const float*)d_in[2];
    const float* a2w = (const float*)d_in[3];
    const float* a2b = (const float*)d_in[4];
    const float* a3w = (const float*)d_in[5];
    const float* a3b = (const float*)d_in[6];
    const float* b1w = (const float*)d_in[7];
    const float* b1b = (const float*)d_in[8];
    const float* b2w = (const float*)d_in[9];
    const float* b2b = (const float*)d_in[10];
    const float* wgt = (const float*)d_in[11];
    float* out = (float*)d_out;

    char* ws = (char*)d_ws;
    float* pooled        = (float*)(ws);                 // 1024 B
    unsigned short* a1A  = (unsigned short*)(ws + 2048); // 9216 B
    unsigned short* wAf  = (unsigned short*)(ws + 11264);// 18432 B
    unsigned short* xbf  = (unsigned short*)(ws + 32768);// 18874368 B (bf16 x, pixel-major)

    convert_pool_prep<<<dim3(CONV_BLKS + POOL_BLKS + 9), dim3(256), 0, stream>>>(
        x, a1w, wgt, pooled, a1A, wAf, xbf);
    laconv_kernel<<<dim3(12 * 12 * B_), dim3(256), 0, stream>>>(
        xbf, a1b, a2w, a2b, a3w, a3b, a1A, wAf, pooled, b1w, b1b, b2w, b2b, out);
    (void)in_sizes; (void)n_in; (void)out_size; (void)ws_size;
}